// Round 6
// baseline (324.804 us; speedup 1.0000x reference)
//
#include <hip/hip_runtime.h>

// VectorQuantizer: x (64,64,64,64) f32, embeddings (64,512) f32
// rows N = 64^3 = 262144, D = 64, K = 512
// out: quantized_st (16777216 f32) ++ loss (1 f32)
//
// Round 13 RESUBMIT (r5 bench was GPUAcquisitionTimeout - never ran).
// Two-term MFMA approx (z_hi*e_hi + z_hi*e_lo, both accumulated into the
// SAME f32 acc -> zero extra VALU, 16 MFMAs/t). Residual error is
// z_lo*(e_j-e_k) only: sigma ~9.2e-5. Window 12 -> 8 steps (worst-binade
// coverage (8-2)*2.44e-4 = 1.46e-3 ~= 16 sigma). Rationale: r12 showed
// vq_fixup as top dispatch (138us, occ 0.05%, 11.3MB rewrites = ~44K
// flipped rows, per-flip single-address loss atomics). Single-term error
// (3.2e-3) forced the wide window and thousands of flips; 30x smaller
// error collapses flips -> fixup shrinks without touching its bit-exact
// code. MFMA was 7% utilized - the extra 8 MFMAs/t are nearly free.
// Fixup + loss semantics byte-identical (absmax 0.0 rounds 2-12).

typedef __attribute__((ext_vector_type(8))) _Float16 f16x8;
typedef __attribute__((ext_vector_type(4))) float f32x4;

#define NROWS   262144
#define DIM     64
#define KCODES  512
#define NELEM   16777216
#define LISTCAP 65536

// ws layout (float offsets)
#define WS_ET     0        // 512*64 code-major embeddings
#define WS_EN     32768    // exact enorm (numpy rounding)
#define WS_EN8    33280    // enorm + 8 (approx domain, keeps d positive)
#define WS_PACKH  33792    // uint4[4096]: e_hi fp16 B-fragments (16x16x32 order)
#define WS_PACKL  50176    // uint4[4096]: e_lo fp16 B-fragments
#define WS_CNT    66560    // flag counter (int)
#define WS_LIST   66576    // flagged rows: (row<<9)|idx

union FragH { uint4 q; f16x8 v; _Float16 u[8]; };

// ---- prep (blocks 0-1): ET transpose, exact enorm (R(e*e) + sequential
// adds), enorm+8, zero loss + flag counter.
// ---- pack (blocks 2-17): e_hi = fp16(e), e_lo = fp16(e - (f32)e_hi)
// into 16x16x32 B-fragment order:
// frag id = (t*2+c)*64+lane holds B[k = c*32+(lane>>4)*8+j][n = t*16+(lane&15)]
__global__ void vq_prep(const float* __restrict__ E, float* __restrict__ ET,
                        float* __restrict__ en, float* __restrict__ en8,
                        float* __restrict__ loss, int* __restrict__ cnt,
                        uint4* __restrict__ packH, uint4* __restrict__ packL) {
    const int bid = blockIdx.x;
    if (bid < 2) {
        int k = bid * 256 + threadIdx.x;          // 0..511
        if (k == 0) *loss = 0.f;
        if (k == 1) *cnt = 0;
        float s = 0.f;
        for (int i = 0; i < DIM; ++i) {
            float v = E[i * KCODES + k];
            ET[k * DIM + i] = v;
            s = __fadd_rn(s, __fmul_rn(v, v));
        }
        en[k] = s;
        en8[k] = __fadd_rn(s, 8.0f);
    } else {
        const int id = (bid - 2) * 256 + threadIdx.x;  // 0..4095
        const int lane = id & 63;
        const int c = (id >> 6) & 1;
        const int t = id >> 7;
        const int n = t * 16 + (lane & 15);
        const int kb = c * 32 + (lane >> 4) * 8;
        FragH H, L;
        #pragma unroll
        for (int j = 0; j < 8; ++j) {
            float v = E[(size_t)(kb + j) * KCODES + n];
            _Float16 hi = (_Float16)v;
            float lo = __fadd_rn(v, -(float)hi);
            H.u[j] = hi;
            L.u[j] = (_Float16)lo;
        }
        packH[id] = H.q;
        packL[id] = L.q;
    }
}

// ---- main: 4 waves x 64 rows = 256 rows/block, grid 1024. No LDS.
// Each wave: FOUR 16-row M-tiles over 32 col-tiles; 16 MFMA per t
// (8 hi-term + 8 lo-term into the same acc).
// 16x16x32 layouts: A[m = lane&15][k = (lane>>4)*8+j];
// C col (code) = lane&15, row (z-row) = (lane>>4)*4 + reg  (m89-verified).
__global__ __launch_bounds__(256, 4)
void vq_main(const float* __restrict__ x, const float* __restrict__ ET,
             const float* __restrict__ en8, const uint4* __restrict__ packH,
             const uint4* __restrict__ packL,
             float* __restrict__ outp, float* __restrict__ loss,
             int* __restrict__ cnt, int* __restrict__ list) {
    const int tid  = threadIdx.x;
    const int wv   = tid >> 6;
    const int lane = tid & 63;
    const int l15  = lane & 15;
    const int g    = lane >> 4;                  // lane group 0..3
    const size_t rowbase = (size_t)blockIdx.x * 256 + (size_t)wv * 64;

    // A fragments: z_hi fp16 only; ah[mt][kc]: row = mt*16+l15, k = kc*32+g*8+j
    FragH ah[4][2];
    #pragma unroll
    for (int mt = 0; mt < 4; ++mt) {
        const float* xr = x + (rowbase + mt * 16 + l15) * DIM;
        #pragma unroll
        for (int kc = 0; kc < 2; ++kc) {
            const float* xp = xr + kc * 32 + g * 8;
            float4 p0 = *(const float4*)xp;
            float4 p1 = *(const float4*)(xp + 4);
            ah[mt][kc].u[0] = (_Float16)p0.x; ah[mt][kc].u[1] = (_Float16)p0.y;
            ah[mt][kc].u[2] = (_Float16)p0.z; ah[mt][kc].u[3] = (_Float16)p0.w;
            ah[mt][kc].u[4] = (_Float16)p1.x; ah[mt][kc].u[5] = (_Float16)p1.y;
            ah[mt][kc].u[6] = (_Float16)p1.z; ah[mt][kc].u[7] = (_Float16)p1.w;
        }
    }

    // per-row-slot top-2 keys; slot s = mt*4 + r covers row mt*16 + g*4 + r
    unsigned int b1[16], b2[16];
    #pragma unroll
    for (int s = 0; s < 16; ++s) { b1[s] = 0xFFFFFFFFu; b2[s] = 0xFFFFFFFFu; }

    // Register double-buffer: prefetch t+1's B-fragments before t's MFMAs.
    FragH bh[2], bl[2], bnh[2], bnl[2];
    bh[0].q = packH[lane];       bh[1].q = packH[64 + lane];
    bl[0].q = packL[lane];       bl[1].q = packL[64 + lane];

    #pragma unroll 2
    for (int t = 0; t < 32; ++t) {
        const float ev = en8[t * 16 + l15];          // L1-hot 2KB, 4-way bcast
        if (t < 31) {
            bnh[0].q = packH[(t + 1) * 128 + lane];      // L1/L2-hot
            bnh[1].q = packH[(t + 1) * 128 + 64 + lane];
            bnl[0].q = packL[(t + 1) * 128 + lane];
            bnl[1].q = packL[(t + 1) * 128 + 64 + lane];
        }
        f32x4 acc[4];
        #pragma unroll
        for (int mt = 0; mt < 4; ++mt) {
            acc[mt][0] = 0.f; acc[mt][1] = 0.f; acc[mt][2] = 0.f; acc[mt][3] = 0.f;
        }
        #pragma unroll
        for (int kc = 0; kc < 2; ++kc)                   // z_hi * e_hi
            #pragma unroll
            for (int mt = 0; mt < 4; ++mt)
                acc[mt] = __builtin_amdgcn_mfma_f32_16x16x32_f16(
                              ah[mt][kc].v, bh[kc].v, acc[mt], 0, 0, 0);
        #pragma unroll
        for (int kc = 0; kc < 2; ++kc)                   // + z_hi * e_lo
            #pragma unroll
            for (int mt = 0; mt < 4; ++mt)
                acc[mt] = __builtin_amdgcn_mfma_f32_16x16x32_f16(
                              ah[mt][kc].v, bl[kc].v, acc[mt], 0, 0, 0);
        // keys: d = enorm+8 - 2*sim > 0; (bits & ~511) | col sorts by dist
        const unsigned int colv = (unsigned int)(t * 16 + l15);
        #pragma unroll
        for (int mt = 0; mt < 4; ++mt)
            #pragma unroll
            for (int r = 0; r < 4; ++r) {
                const int s = mt * 4 + r;
                float d = fmaf(-2.f, acc[mt][r], ev);
                unsigned int key = (__float_as_uint(d) & 0xFFFFFE00u) | colv;
                unsigned int n1 = min(key, b1[s]);
                unsigned int mx = max(key, b1[s]);
                b2[s] = min(b2[s], mx);
                b1[s] = n1;
            }
        bh[0] = bnh[0]; bh[1] = bnh[1];
        bl[0] = bnl[0]; bl[1] = bnl[1];
    }

    // merge top-2 across the 16-lane group; slot s -> row mt*16 + g*4 + r.
    // Flags are BUFFERED in registers (static index) -- no per-row atomics.
    unsigned int flagmask = 0;
    unsigned int ent[16];
    float lsq = 0.f;
    #pragma unroll
    for (int s = 0; s < 16; ++s) {
        unsigned int B1 = b1[s], B2 = b2[s];
        #pragma unroll
        for (int off = 1; off <= 8; off <<= 1) {
            unsigned int o1 = (unsigned int)__shfl_xor((int)B1, off, 64);
            unsigned int o2 = (unsigned int)__shfl_xor((int)B2, off, 64);
            unsigned int n1 = min(B1, o1);
            unsigned int mx = max(B1, o1);
            B2 = min(min(B2, o2), mx);
            B1 = n1;
        }
        const int idx = (int)(B1 & 511u);
        const size_t row = rowbase + (size_t)((s >> 2) * 16 + g * 4 + (s & 3));
        // 8-step window: worst-binade coverage (8-2)*2.44e-4 = 1.46e-3 >>
        // 10-sigma residual z_lo*(e_j-e_k) ~= 9.2e-4. (Two-term approx:
        // only the z_lo cross term remains; e re-quantization ~2^-22.)
        if (l15 == 0 &&
            ((B2 & 0xFFFFFE00u) - (B1 & 0xFFFFFE00u)) <= (8u << 9)) {
            flagmask |= (1u << s);
        }
        ent[s] = ((unsigned int)row << 9) | (unsigned int)idx;
        // out = R(x + R(q - x)); 16 lanes x 4 cols cover the row
        const float4 q4 = ((const float4*)(ET + idx * DIM))[l15];
        const float4 x4 = ((const float4*)(x + row * DIM))[l15];
        float d0 = __fadd_rn(q4.x, -x4.x);
        float d1 = __fadd_rn(q4.y, -x4.y);
        float d2 = __fadd_rn(q4.z, -x4.z);
        float d3 = __fadd_rn(q4.w, -x4.w);
        float4 o;
        o.x = __fadd_rn(x4.x, d0); o.y = __fadd_rn(x4.y, d1);
        o.z = __fadd_rn(x4.z, d2); o.w = __fadd_rn(x4.w, d3);
        ((float4*)(outp + row * DIM))[l15] = o;
        lsq = fmaf(d0, d0, lsq);
        lsq = fmaf(d1, d1, lsq);
        lsq = fmaf(d2, d2, lsq);
        lsq = fmaf(d3, d3, lsq);
    }

    // ONE flag atomic per wave: total over the 4 l15==0 lanes, then each
    // writes its entries at base + prefix (entry set identical to per-row
    // atomics; only list order differs -- fixup is order-independent).
    {
        int fc = __popc(flagmask);               // 0 on l15!=0 lanes
        int tot = fc + __shfl_xor(fc, 16, 64);
        tot += __shfl_xor(tot, 32, 64);          // lanes {0,16,32,48} share tot
        const int c0 = __shfl(fc,  0, 64);
        const int c1 = __shfl(fc, 16, 64);
        const int c2 = __shfl(fc, 32, 64);
        int base = 0;
        if (lane == 0 && tot > 0) base = atomicAdd(cnt, tot);
        base = __shfl(base, 0, 64);
        if (l15 == 0 && flagmask) {
            int pos = base + (g > 0 ? c0 : 0) + (g > 1 ? c1 : 0) + (g > 2 ? c2 : 0);
            #pragma unroll
            for (int s = 0; s < 16; ++s)
                if (flagmask & (1u << s)) {
                    if (pos < LISTCAP) list[pos] = (int)ent[s];
                    ++pos;
                }
        }
    }

    #pragma unroll
    for (int off = 32; off > 0; off >>= 1) lsq += __shfl_xor(lsq, off, 64);
    if (lane == 0) atomicAdd(loss, lsq * (1.25f / (float)NELEM));
}

// ---- fixup: 8 flagged rows PER WAVE (E read once per 8 rows). z rows
// register-distributed (lane i holds z[i]); broadcasts via shfl. Bit-exact
// numpy emulation: AVX512-pairwise xnorm (shfl tree, same add order),
// sequential-i FMA chains, first-index argmin. Rewrites rows that changed.
__global__ __launch_bounds__(256, 1)
void vq_fixup(const float* __restrict__ x, const float* __restrict__ E,
              const float* __restrict__ ET, const float* __restrict__ en,
              float* __restrict__ outp, float* __restrict__ loss,
              const int* __restrict__ cnt, const int* __restrict__ list) {
    const int tid  = threadIdx.x;
    const int wv   = tid >> 6;
    const int lane = tid & 63;
    int total = *cnt;
    if (total > LISTCAP) total = LISTCAP;
    const int wgid   = blockIdx.x * 4 + wv;
    const int nwaves = gridDim.x * 4;

    // this lane's 8 codes' exact enorm (reused across all rows)
    float enk[8];
    {
        float4 e0 = ((const float4*)(en + lane * 8))[0];
        float4 e1 = ((const float4*)(en + lane * 8))[1];
        enk[0] = e0.x; enk[1] = e0.y; enk[2] = e0.z; enk[3] = e0.w;
        enk[4] = e1.x; enk[5] = e1.y; enk[6] = e1.z; enk[7] = e1.w;
    }

    for (int base = wgid * 8; base < total; base += nwaves * 8) {
        const int nrows = min(8, total - base);
        int ent = 0;
        if (lane < 8 && base + lane < total) ent = list[base + lane];

        // z register-distributed: zreg[r8] = x[row_r8 * 64 + lane]
        float zreg[8];
        #pragma unroll
        for (int r8 = 0; r8 < 8; ++r8) {
            int er = __shfl(ent, r8, 64);
            zreg[r8] = x[(size_t)(er >> 9) * DIM + lane];
        }

        // exact xnorm per row: numpy AVX512 pairwise tree via shuffles
        float xnr[8];
        #pragma unroll
        for (int r8 = 0; r8 < 8; ++r8) {
            float s = __fmul_rn(zreg[r8], zreg[r8]);       // R(z*z) per elem
            int j = lane & 15;
            float a = __fadd_rn(__shfl(s, j, 64),      __shfl(s, j + 16, 64));
            float b = __fadd_rn(__shfl(s, j + 32, 64), __shfl(s, j + 48, 64));
            float v = __fadd_rn(a, b);                     // lane holds v_{lane&15}
            int j8 = lane & 7;
            float u = __fadd_rn(__shfl(v, j8, 64), __shfl(v, j8 + 8, 64));
            int j4 = lane & 3;
            float c = __fadd_rn(__shfl(u, j4, 64), __shfl(u, j4 + 4, 64));
            xnr[r8] = __fadd_rn(__fadd_rn(__shfl(c, 0, 64), __shfl(c, 2, 64)),
                                __fadd_rn(__shfl(c, 1, 64), __shfl(c, 3, 64)));
        }

        // exact sims for 8 rows x this lane's 8 codes; sequential-i chains.
        float acc[8][8];
        #pragma unroll
        for (int r8 = 0; r8 < 8; ++r8)
            #pragma unroll
            for (int j = 0; j < 8; ++j) acc[r8][j] = 0.f;
        const float* Ep = E + lane * 8;
        #pragma unroll 4
        for (int i = 0; i < DIM; ++i) {
            const float4 e0 = ((const float4*)(Ep + (size_t)i * KCODES))[0];
            const float4 e1 = ((const float4*)(Ep + (size_t)i * KCODES))[1];
            float ev[8] = {e0.x, e0.y, e0.z, e0.w, e1.x, e1.y, e1.z, e1.w};
            #pragma unroll
            for (int r8 = 0; r8 < 8; ++r8) {
                const float zi = __shfl(zreg[r8], i, 64);
                #pragma unroll
                for (int j = 0; j < 8; ++j)
                    acc[r8][j] = __fmaf_rn(zi, ev[j], acc[r8][j]);
            }
        }

        // per row: dist, first-index argmin, rewrite if changed
        for (int r8 = 0; r8 < nrows; ++r8) {
            const int er  = __shfl(ent, r8, 64);
            const int row = er >> 9;
            const int old = er & 511;
            float bd = 3.4e38f; int bk = 0;
            #pragma unroll
            for (int j = 0; j < 8; ++j) {
                int k = lane * 8 + j;
                float t1 = __fadd_rn(xnr[r8], enk[j]);
                float d  = __fadd_rn(t1, -2.0f * acc[r8][j]);
                if (d < bd) { bd = d; bk = k; }
            }
            #pragma unroll
            for (int off = 1; off <= 32; off <<= 1) {
                float od = __shfl_xor(bd, off, 64);
                int   ok = __shfl_xor(bk, off, 64);
                if (od < bd || (od == bd && ok < bk)) { bd = od; bk = ok; }
            }
            if (bk != old) {
                const float xl = zreg[r8];              // x[row*64 + lane]
                const float qn = ET[bk * DIM + lane];
                const float qo = ET[old * DIM + lane];
                const float dn = __fadd_rn(qn, -xl);
                const float dd = __fadd_rn(qo, -xl);
                outp[(size_t)row * DIM + lane] = __fadd_rn(xl, dn);
                float dl = __fsub_rn(__fmul_rn(dn, dn), __fmul_rn(dd, dd));
                #pragma unroll
                for (int off = 32; off > 0; off >>= 1) dl += __shfl_xor(dl, off, 64);
                if (lane == 0) atomicAdd(loss, dl * (1.25f / (float)NELEM));
            }
        }
    }
}

extern "C" void kernel_launch(void* const* d_in, const int* in_sizes, int n_in,
                              void* d_out, int out_size, void* d_ws, size_t ws_size,
                              hipStream_t stream) {
    const float* x = (const float*)d_in[0];
    const float* E = (const float*)d_in[1];
    float* out  = (float*)d_out;
    float* loss = out + NELEM;
    float* ws = (float*)d_ws;
    float* ET    = ws + WS_ET;
    float* en    = ws + WS_EN;
    float* en8   = ws + WS_EN8;
    uint4* packH = (uint4*)(ws + WS_PACKH);
    uint4* packL = (uint4*)(ws + WS_PACKL);
    int* cnt  = (int*)(ws + WS_CNT);
    int* list = (int*)(ws + WS_LIST);

    vq_prep<<<18, 256, 0, stream>>>(E, ET, en, en8, loss, cnt, packH, packL);
    vq_main<<<1024, 256, 0, stream>>>(x, ET, en8, packH, packL, out, loss, cnt, list);
    vq_fixup<<<512, 256, 0, stream>>>(x, E, ET, en, out, loss, cnt, list);
}

// Round 7
// 211.230 us; speedup vs baseline: 1.5377x; 1.5377x over previous
//
#include <hip/hip_runtime.h>

// VectorQuantizer: x (64,64,64,64) f32, embeddings (64,512) f32
// rows N = 64^3 = 262144, D = 64, K = 512
// out: quantized_st (16777216 f32) ++ loss (1 f32)
//
// Round 14: r13 two-term kernel with the spill fixed. r13's
// __launch_bounds__(256,4) pinned the allocator at 64 VGPRs while live
// state is ~120 (ah 16 + b1/b2 32 + bh/bl/bnh/bnl 32 + acc 16 + misc)
// -> in-loop scratch spill (FETCH 70->315MB, WRITE 72->210MB, 93->217us).
// Same failure mode as r10. Plain __launch_bounds__(256) (r8-style, which
// allocated 104 VGPRs spill-free) lets the compiler take ~130 regs;
// occupancy drops to ~2 blocks/CU but r8/r9/r11 proved dur is insensitive
// to occupancy 18-45%. Two-term approx unchanged: z_hi*e_hi + z_hi*e_lo
// into the same f32 acc; residual z_lo*(e_j-e_k) sigma ~9.2e-5; 8-step
// window coverage (8-2)*2.44e-4 = 1.46e-3 ~= 16 sigma. Fixup + loss
// semantics byte-identical (absmax 0.0 rounds 2-13).

typedef __attribute__((ext_vector_type(8))) _Float16 f16x8;
typedef __attribute__((ext_vector_type(4))) float f32x4;

#define NROWS   262144
#define DIM     64
#define KCODES  512
#define NELEM   16777216
#define LISTCAP 65536

// ws layout (float offsets)
#define WS_ET     0        // 512*64 code-major embeddings
#define WS_EN     32768    // exact enorm (numpy rounding)
#define WS_EN8    33280    // enorm + 8 (approx domain, keeps d positive)
#define WS_PACKH  33792    // uint4[4096]: e_hi fp16 B-fragments (16x16x32 order)
#define WS_PACKL  50176    // uint4[4096]: e_lo fp16 B-fragments
#define WS_CNT    66560    // flag counter (int)
#define WS_LIST   66576    // flagged rows: (row<<9)|idx

union FragH { uint4 q; f16x8 v; _Float16 u[8]; };

// ---- prep (blocks 0-1): ET transpose, exact enorm (R(e*e) + sequential
// adds), enorm+8, zero loss + flag counter.
// ---- pack (blocks 2-17): e_hi = fp16(e), e_lo = fp16(e - (f32)e_hi)
// into 16x16x32 B-fragment order:
// frag id = (t*2+c)*64+lane holds B[k = c*32+(lane>>4)*8+j][n = t*16+(lane&15)]
__global__ void vq_prep(const float* __restrict__ E, float* __restrict__ ET,
                        float* __restrict__ en, float* __restrict__ en8,
                        float* __restrict__ loss, int* __restrict__ cnt,
                        uint4* __restrict__ packH, uint4* __restrict__ packL) {
    const int bid = blockIdx.x;
    if (bid < 2) {
        int k = bid * 256 + threadIdx.x;          // 0..511
        if (k == 0) *loss = 0.f;
        if (k == 1) *cnt = 0;
        float s = 0.f;
        for (int i = 0; i < DIM; ++i) {
            float v = E[i * KCODES + k];
            ET[k * DIM + i] = v;
            s = __fadd_rn(s, __fmul_rn(v, v));
        }
        en[k] = s;
        en8[k] = __fadd_rn(s, 8.0f);
    } else {
        const int id = (bid - 2) * 256 + threadIdx.x;  // 0..4095
        const int lane = id & 63;
        const int c = (id >> 6) & 1;
        const int t = id >> 7;
        const int n = t * 16 + (lane & 15);
        const int kb = c * 32 + (lane >> 4) * 8;
        FragH H, L;
        #pragma unroll
        for (int j = 0; j < 8; ++j) {
            float v = E[(size_t)(kb + j) * KCODES + n];
            _Float16 hi = (_Float16)v;
            float lo = __fadd_rn(v, -(float)hi);
            H.u[j] = hi;
            L.u[j] = (_Float16)lo;
        }
        packH[id] = H.q;
        packL[id] = L.q;
    }
}

// ---- main: 4 waves x 64 rows = 256 rows/block, grid 1024. No LDS.
// Each wave: FOUR 16-row M-tiles over 32 col-tiles; 16 MFMA per t
// (8 hi-term + 8 lo-term into the same acc).
// 16x16x32 layouts: A[m = lane&15][k = (lane>>4)*8+j];
// C col (code) = lane&15, row (z-row) = (lane>>4)*4 + reg  (m89-verified).
// Plain __launch_bounds__(256): let the allocator take ~130 VGPRs
// (spill-free) instead of pinning 64 and spilling (r13 failure).
__global__ __launch_bounds__(256)
void vq_main(const float* __restrict__ x, const float* __restrict__ ET,
             const float* __restrict__ en8, const uint4* __restrict__ packH,
             const uint4* __restrict__ packL,
             float* __restrict__ outp, float* __restrict__ loss,
             int* __restrict__ cnt, int* __restrict__ list) {
    const int tid  = threadIdx.x;
    const int wv   = tid >> 6;
    const int lane = tid & 63;
    const int l15  = lane & 15;
    const int g    = lane >> 4;                  // lane group 0..3
    const size_t rowbase = (size_t)blockIdx.x * 256 + (size_t)wv * 64;

    // A fragments: z_hi fp16 only; ah[mt][kc]: row = mt*16+l15, k = kc*32+g*8+j
    FragH ah[4][2];
    #pragma unroll
    for (int mt = 0; mt < 4; ++mt) {
        const float* xr = x + (rowbase + mt * 16 + l15) * DIM;
        #pragma unroll
        for (int kc = 0; kc < 2; ++kc) {
            const float* xp = xr + kc * 32 + g * 8;
            float4 p0 = *(const float4*)xp;
            float4 p1 = *(const float4*)(xp + 4);
            ah[mt][kc].u[0] = (_Float16)p0.x; ah[mt][kc].u[1] = (_Float16)p0.y;
            ah[mt][kc].u[2] = (_Float16)p0.z; ah[mt][kc].u[3] = (_Float16)p0.w;
            ah[mt][kc].u[4] = (_Float16)p1.x; ah[mt][kc].u[5] = (_Float16)p1.y;
            ah[mt][kc].u[6] = (_Float16)p1.z; ah[mt][kc].u[7] = (_Float16)p1.w;
        }
    }

    // per-row-slot top-2 keys; slot s = mt*4 + r covers row mt*16 + g*4 + r
    unsigned int b1[16], b2[16];
    #pragma unroll
    for (int s = 0; s < 16; ++s) { b1[s] = 0xFFFFFFFFu; b2[s] = 0xFFFFFFFFu; }

    // Register double-buffer: prefetch t+1's B-fragments before t's MFMAs.
    FragH bh[2], bl[2], bnh[2], bnl[2];
    bh[0].q = packH[lane];       bh[1].q = packH[64 + lane];
    bl[0].q = packL[lane];       bl[1].q = packL[64 + lane];

    #pragma unroll 2
    for (int t = 0; t < 32; ++t) {
        const float ev = en8[t * 16 + l15];          // L1-hot 2KB, 4-way bcast
        if (t < 31) {
            bnh[0].q = packH[(t + 1) * 128 + lane];      // L1/L2-hot
            bnh[1].q = packH[(t + 1) * 128 + 64 + lane];
            bnl[0].q = packL[(t + 1) * 128 + lane];
            bnl[1].q = packL[(t + 1) * 128 + 64 + lane];
        }
        f32x4 acc[4];
        #pragma unroll
        for (int mt = 0; mt < 4; ++mt) {
            acc[mt][0] = 0.f; acc[mt][1] = 0.f; acc[mt][2] = 0.f; acc[mt][3] = 0.f;
        }
        #pragma unroll
        for (int kc = 0; kc < 2; ++kc)                   // z_hi * e_hi
            #pragma unroll
            for (int mt = 0; mt < 4; ++mt)
                acc[mt] = __builtin_amdgcn_mfma_f32_16x16x32_f16(
                              ah[mt][kc].v, bh[kc].v, acc[mt], 0, 0, 0);
        #pragma unroll
        for (int kc = 0; kc < 2; ++kc)                   // + z_hi * e_lo
            #pragma unroll
            for (int mt = 0; mt < 4; ++mt)
                acc[mt] = __builtin_amdgcn_mfma_f32_16x16x32_f16(
                              ah[mt][kc].v, bl[kc].v, acc[mt], 0, 0, 0);
        // keys: d = enorm+8 - 2*sim > 0; (bits & ~511) | col sorts by dist
        const unsigned int colv = (unsigned int)(t * 16 + l15);
        #pragma unroll
        for (int mt = 0; mt < 4; ++mt)
            #pragma unroll
            for (int r = 0; r < 4; ++r) {
                const int s = mt * 4 + r;
                float d = fmaf(-2.f, acc[mt][r], ev);
                unsigned int key = (__float_as_uint(d) & 0xFFFFFE00u) | colv;
                unsigned int n1 = min(key, b1[s]);
                unsigned int mx = max(key, b1[s]);
                b2[s] = min(b2[s], mx);
                b1[s] = n1;
            }
        bh[0] = bnh[0]; bh[1] = bnh[1];
        bl[0] = bnl[0]; bl[1] = bnl[1];
    }

    // merge top-2 across the 16-lane group; slot s -> row mt*16 + g*4 + r.
    // Flags are BUFFERED in registers (static index) -- no per-row atomics.
    unsigned int flagmask = 0;
    unsigned int ent[16];
    float lsq = 0.f;
    #pragma unroll
    for (int s = 0; s < 16; ++s) {
        unsigned int B1 = b1[s], B2 = b2[s];
        #pragma unroll
        for (int off = 1; off <= 8; off <<= 1) {
            unsigned int o1 = (unsigned int)__shfl_xor((int)B1, off, 64);
            unsigned int o2 = (unsigned int)__shfl_xor((int)B2, off, 64);
            unsigned int n1 = min(B1, o1);
            unsigned int mx = max(B1, o1);
            B2 = min(min(B2, o2), mx);
            B1 = n1;
        }
        const int idx = (int)(B1 & 511u);
        const size_t row = rowbase + (size_t)((s >> 2) * 16 + g * 4 + (s & 3));
        // 8-step window: worst-binade coverage (8-2)*2.44e-4 = 1.46e-3 >>
        // 10-sigma residual z_lo*(e_j-e_k) ~= 9.2e-4. (Two-term approx:
        // only the z_lo cross term remains; e re-quantization ~2^-22.)
        if (l15 == 0 &&
            ((B2 & 0xFFFFFE00u) - (B1 & 0xFFFFFE00u)) <= (8u << 9)) {
            flagmask |= (1u << s);
        }
        ent[s] = ((unsigned int)row << 9) | (unsigned int)idx;
        // out = R(x + R(q - x)); 16 lanes x 4 cols cover the row
        const float4 q4 = ((const float4*)(ET + idx * DIM))[l15];
        const float4 x4 = ((const float4*)(x + row * DIM))[l15];
        float d0 = __fadd_rn(q4.x, -x4.x);
        float d1 = __fadd_rn(q4.y, -x4.y);
        float d2 = __fadd_rn(q4.z, -x4.z);
        float d3 = __fadd_rn(q4.w, -x4.w);
        float4 o;
        o.x = __fadd_rn(x4.x, d0); o.y = __fadd_rn(x4.y, d1);
        o.z = __fadd_rn(x4.z, d2); o.w = __fadd_rn(x4.w, d3);
        ((float4*)(outp + row * DIM))[l15] = o;
        lsq = fmaf(d0, d0, lsq);
        lsq = fmaf(d1, d1, lsq);
        lsq = fmaf(d2, d2, lsq);
        lsq = fmaf(d3, d3, lsq);
    }

    // ONE flag atomic per wave: total over the 4 l15==0 lanes, then each
    // writes its entries at base + prefix (entry set identical to per-row
    // atomics; only list order differs -- fixup is order-independent).
    {
        int fc = __popc(flagmask);               // 0 on l15!=0 lanes
        int tot = fc + __shfl_xor(fc, 16, 64);
        tot += __shfl_xor(tot, 32, 64);          // lanes {0,16,32,48} share tot
        const int c0 = __shfl(fc,  0, 64);
        const int c1 = __shfl(fc, 16, 64);
        const int c2 = __shfl(fc, 32, 64);
        int base = 0;
        if (lane == 0 && tot > 0) base = atomicAdd(cnt, tot);
        base = __shfl(base, 0, 64);
        if (l15 == 0 && flagmask) {
            int pos = base + (g > 0 ? c0 : 0) + (g > 1 ? c1 : 0) + (g > 2 ? c2 : 0);
            #pragma unroll
            for (int s = 0; s < 16; ++s)
                if (flagmask & (1u << s)) {
                    if (pos < LISTCAP) list[pos] = (int)ent[s];
                    ++pos;
                }
        }
    }

    #pragma unroll
    for (int off = 32; off > 0; off >>= 1) lsq += __shfl_xor(lsq, off, 64);
    if (lane == 0) atomicAdd(loss, lsq * (1.25f / (float)NELEM));
}

// ---- fixup: 8 flagged rows PER WAVE (E read once per 8 rows). z rows
// register-distributed (lane i holds z[i]); broadcasts via shfl. Bit-exact
// numpy emulation: AVX512-pairwise xnorm (shfl tree, same add order),
// sequential-i FMA chains, first-index argmin. Rewrites rows that changed.
__global__ __launch_bounds__(256, 1)
void vq_fixup(const float* __restrict__ x, const float* __restrict__ E,
              const float* __restrict__ ET, const float* __restrict__ en,
              float* __restrict__ outp, float* __restrict__ loss,
              const int* __restrict__ cnt, const int* __restrict__ list) {
    const int tid  = threadIdx.x;
    const int wv   = tid >> 6;
    const int lane = tid & 63;
    int total = *cnt;
    if (total > LISTCAP) total = LISTCAP;
    const int wgid   = blockIdx.x * 4 + wv;
    const int nwaves = gridDim.x * 4;

    // this lane's 8 codes' exact enorm (reused across all rows)
    float enk[8];
    {
        float4 e0 = ((const float4*)(en + lane * 8))[0];
        float4 e1 = ((const float4*)(en + lane * 8))[1];
        enk[0] = e0.x; enk[1] = e0.y; enk[2] = e0.z; enk[3] = e0.w;
        enk[4] = e1.x; enk[5] = e1.y; enk[6] = e1.z; enk[7] = e1.w;
    }

    for (int base = wgid * 8; base < total; base += nwaves * 8) {
        const int nrows = min(8, total - base);
        int ent = 0;
        if (lane < 8 && base + lane < total) ent = list[base + lane];

        // z register-distributed: zreg[r8] = x[row_r8 * 64 + lane]
        float zreg[8];
        #pragma unroll
        for (int r8 = 0; r8 < 8; ++r8) {
            int er = __shfl(ent, r8, 64);
            zreg[r8] = x[(size_t)(er >> 9) * DIM + lane];
        }

        // exact xnorm per row: numpy AVX512 pairwise tree via shuffles
        float xnr[8];
        #pragma unroll
        for (int r8 = 0; r8 < 8; ++r8) {
            float s = __fmul_rn(zreg[r8], zreg[r8]);       // R(z*z) per elem
            int j = lane & 15;
            float a = __fadd_rn(__shfl(s, j, 64),      __shfl(s, j + 16, 64));
            float b = __fadd_rn(__shfl(s, j + 32, 64), __shfl(s, j + 48, 64));
            float v = __fadd_rn(a, b);                     // lane holds v_{lane&15}
            int j8 = lane & 7;
            float u = __fadd_rn(__shfl(v, j8, 64), __shfl(v, j8 + 8, 64));
            int j4 = lane & 3;
            float c = __fadd_rn(__shfl(u, j4, 64), __shfl(u, j4 + 4, 64));
            xnr[r8] = __fadd_rn(__fadd_rn(__shfl(c, 0, 64), __shfl(c, 2, 64)),
                                __fadd_rn(__shfl(c, 1, 64), __shfl(c, 3, 64)));
        }

        // exact sims for 8 rows x this lane's 8 codes; sequential-i chains.
        float acc[8][8];
        #pragma unroll
        for (int r8 = 0; r8 < 8; ++r8)
            #pragma unroll
            for (int j = 0; j < 8; ++j) acc[r8][j] = 0.f;
        const float* Ep = E + lane * 8;
        #pragma unroll 4
        for (int i = 0; i < DIM; ++i) {
            const float4 e0 = ((const float4*)(Ep + (size_t)i * KCODES))[0];
            const float4 e1 = ((const float4*)(Ep + (size_t)i * KCODES))[1];
            float ev[8] = {e0.x, e0.y, e0.z, e0.w, e1.x, e1.y, e1.z, e1.w};
            #pragma unroll
            for (int r8 = 0; r8 < 8; ++r8) {
                const float zi = __shfl(zreg[r8], i, 64);
                #pragma unroll
                for (int j = 0; j < 8; ++j)
                    acc[r8][j] = __fmaf_rn(zi, ev[j], acc[r8][j]);
            }
        }

        // per row: dist, first-index argmin, rewrite if changed
        for (int r8 = 0; r8 < nrows; ++r8) {
            const int er  = __shfl(ent, r8, 64);
            const int row = er >> 9;
            const int old = er & 511;
            float bd = 3.4e38f; int bk = 0;
            #pragma unroll
            for (int j = 0; j < 8; ++j) {
                int k = lane * 8 + j;
                float t1 = __fadd_rn(xnr[r8], enk[j]);
                float d  = __fadd_rn(t1, -2.0f * acc[r8][j]);
                if (d < bd) { bd = d; bk = k; }
            }
            #pragma unroll
            for (int off = 1; off <= 32; off <<= 1) {
                float od = __shfl_xor(bd, off, 64);
                int   ok = __shfl_xor(bk, off, 64);
                if (od < bd || (od == bd && ok < bk)) { bd = od; bk = ok; }
            }
            if (bk != old) {
                const float xl = zreg[r8];              // x[row*64 + lane]
                const float qn = ET[bk * DIM + lane];
                const float qo = ET[old * DIM + lane];
                const float dn = __fadd_rn(qn, -xl);
                const float dd = __fadd_rn(qo, -xl);
                outp[(size_t)row * DIM + lane] = __fadd_rn(xl, dn);
                float dl = __fsub_rn(__fmul_rn(dn, dn), __fmul_rn(dd, dd));
                #pragma unroll
                for (int off = 32; off > 0; off >>= 1) dl += __shfl_xor(dl, off, 64);
                if (lane == 0) atomicAdd(loss, dl * (1.25f / (float)NELEM));
            }
        }
    }
}

extern "C" void kernel_launch(void* const* d_in, const int* in_sizes, int n_in,
                              void* d_out, int out_size, void* d_ws, size_t ws_size,
                              hipStream_t stream) {
    const float* x = (const float*)d_in[0];
    const float* E = (const float*)d_in[1];
    float* out  = (float*)d_out;
    float* loss = out + NELEM;
    float* ws = (float*)d_ws;
    float* ET    = ws + WS_ET;
    float* en    = ws + WS_EN;
    float* en8   = ws + WS_EN8;
    uint4* packH = (uint4*)(ws + WS_PACKH);
    uint4* packL = (uint4*)(ws + WS_PACKL);
    int* cnt  = (int*)(ws + WS_CNT);
    int* list = (int*)(ws + WS_LIST);

    vq_prep<<<18, 256, 0, stream>>>(E, ET, en, en8, loss, cnt, packH, packL);
    vq_main<<<1024, 256, 0, stream>>>(x, ET, en8, packH, packL, out, loss, cnt, list);
    vq_fixup<<<512, 256, 0, stream>>>(x, E, ET, en, out, loss, cnt, list);
}